// Round 2
// baseline (8201.436 us; speedup 1.0000x reference)
//
#include <hip/hip_runtime.h>

// ---------------------------------------------------------------------------
// GN_NN_32873679684148: encoder MLP+LN -> 4x GATv2+LN residual -> decoder MLP
// Round 1: fix device abort (suspected d_ws overflow: old layout needed 519MB).
//  - ea stored bf16 (204.8MB) with runtime fallback to chunked recompute
//  - CSR-by-dst aggregation (no atomics in per-layer path)
// N=50000, E=800000, H=128, L=4.
// ---------------------------------------------------------------------------

typedef unsigned short u16;
typedef unsigned int   u32;

#define LEAKY01(a) ((a) > 0.f ? (a) : 0.01f*(a))
#define LEAKY20(a) ((a) > 0.f ? (a) : 0.2f*(a))

__device__ __forceinline__ float bf2f(u16 h) { return __uint_as_float(((u32)h) << 16); }
__device__ __forceinline__ u16 f2bf(float f) {
  u32 u = __float_as_uint(f);
  u32 r = u + 0x7fffu + ((u >> 16) & 1u);   // round-to-nearest-even
  return (u16)(r >> 16);
}
__device__ __forceinline__ float bflo(u32 p) { return __uint_as_float(p << 16); }
__device__ __forceinline__ float bfhi(u32 p) { return __uint_as_float(p & 0xffff0000u); }
__device__ __forceinline__ u32 packbf(float a, float b) {
  return (u32)f2bf(a) | ((u32)f2bf(b) << 16);
}

// ---------------- node encoder: 32 -> 64 -> 96 -> 128 + LN -----------------
__global__ __launch_bounds__(256) void node_enc_kernel(
    const float* __restrict__ x,
    const float* __restrict__ w1, const float* __restrict__ b1,
    const float* __restrict__ w2, const float* __restrict__ b2,
    const float* __restrict__ w3, const float* __restrict__ b3,
    const float* __restrict__ g, const float* __restrict__ bb,
    float* __restrict__ y, int n)
{
  __shared__ float sw1t[32*64];    // transposed [k][j]
  __shared__ float sw3t[96*128];   // transposed [k][j]
  __shared__ float sh1[2][64];
  __shared__ float sh2[2][96];
  __shared__ float sred[2][2][2];
  const int tid = threadIdx.x;
  for (int i = tid; i < 64*32; i += blockDim.x) { int j = i >> 5, k = i & 31; sw1t[k*64 + j] = w1[i]; }
  for (int i = tid; i < 128*96; i += blockDim.x) { int j = i / 96, k = i - j*96; sw3t[k*128 + j] = w3[i]; }
  __syncthreads();
  const int grp = tid >> 7, lt = tid & 127;
  const int wv = (tid >> 6) & 1;
  const int rowsPerIter = gridDim.x * 2;
  const int iters = (n + rowsPerIter - 1) / rowsPerIter;
  for (int it = 0; it < iters; ++it) {
    const int row = blockIdx.x*2 + it*rowsPerIter + grp;
    const bool valid = row < n;
    if (valid && lt < 64) {
      const float* xr_ = x + (long)row*32;
      float a = b1[lt];
      #pragma unroll
      for (int k = 0; k < 32; ++k) a += xr_[k] * sw1t[k*64 + lt];
      sh1[grp][lt] = LEAKY01(a);
    }
    __syncthreads();
    if (valid && lt < 96) {
      float a = b2[lt];
      const float* wr = w2 + lt*64;
      #pragma unroll 8
      for (int k = 0; k < 64; ++k) a += sh1[grp][k] * wr[k];
      sh2[grp][lt] = LEAKY01(a);
    }
    __syncthreads();
    float v = 0.f;
    if (valid) {
      float a = b3[lt];
      #pragma unroll 8
      for (int k = 0; k < 96; ++k) a += sh2[grp][k] * sw3t[k*128 + lt];
      v = a;
    }
    float sum = v, sq = v*v;
    for (int off = 32; off; off >>= 1) { sum += __shfl_down(sum, off, 64); sq += __shfl_down(sq, off, 64); }
    if ((tid & 63) == 0) { sred[grp][wv][0] = sum; sred[grp][wv][1] = sq; }
    __syncthreads();
    if (valid) {
      const float ts = sred[grp][0][0] + sred[grp][1][0];
      const float tq = sred[grp][0][1] + sred[grp][1][1];
      const float mu = ts * (1.f/128.f);
      const float var = tq * (1.f/128.f) - mu*mu;
      const float rs = rsqrtf(var + 1e-5f);
      y[(long)row*128 + lt] = (v - mu) * rs * g[lt] + bb[lt];
    }
    __syncthreads();
  }
}

// ------- edge encoder: 8 -> 48 -> 88 -> 128 + LN, writes bf16 chunk --------
__global__ __launch_bounds__(256) void edge_enc_kernel(
    const float* __restrict__ eat,      // chunk base: ecnt rows of 8
    const float* __restrict__ w1, const float* __restrict__ b1,
    const float* __restrict__ w2, const float* __restrict__ b2,
    const float* __restrict__ w3, const float* __restrict__ b3,
    const float* __restrict__ g, const float* __restrict__ bb,
    u16* __restrict__ ea, int ecnt)
{
  __shared__ float sw1t[8*48];
  __shared__ float sw2t[48*88];
  __shared__ float sw3t[88*128];
  __shared__ float sh1[2][48];
  __shared__ float sh2[2][88];
  __shared__ float sred[2][2][2];
  const int tid = threadIdx.x;
  for (int i = tid; i < 48*8; i += blockDim.x)   { int j = i >> 3, k = i & 7;      sw1t[k*48 + j] = w1[i]; }
  for (int i = tid; i < 88*48; i += blockDim.x)  { int j = i / 48, k = i - j*48;   sw2t[k*88 + j] = w2[i]; }
  for (int i = tid; i < 128*88; i += blockDim.x) { int j = i / 88, k = i - j*88;   sw3t[k*128 + j] = w3[i]; }
  __syncthreads();
  const int grp = tid >> 7, lt = tid & 127;
  const int wv = (tid >> 6) & 1;
  const int rowsPerIter = gridDim.x * 2;
  const int iters = (ecnt + rowsPerIter - 1) / rowsPerIter;
  for (int it = 0; it < iters; ++it) {
    const int row = blockIdx.x*2 + it*rowsPerIter + grp;
    const bool valid = row < ecnt;
    if (valid && lt < 48) {
      const float* er = eat + (long)row*8;
      float a = b1[lt];
      #pragma unroll
      for (int k = 0; k < 8; ++k) a += er[k] * sw1t[k*48 + lt];
      sh1[grp][lt] = LEAKY01(a);
    }
    __syncthreads();
    if (valid && lt < 88) {
      float a = b2[lt];
      #pragma unroll 8
      for (int k = 0; k < 48; ++k) a += sh1[grp][k] * sw2t[k*88 + lt];
      sh2[grp][lt] = LEAKY01(a);
    }
    __syncthreads();
    float v = 0.f;
    if (valid) {
      float a = b3[lt];
      #pragma unroll 8
      for (int k = 0; k < 88; ++k) a += sh2[grp][k] * sw3t[k*128 + lt];
      v = a;
    }
    float sum = v, sq = v*v;
    for (int off = 32; off; off >>= 1) { sum += __shfl_down(sum, off, 64); sq += __shfl_down(sq, off, 64); }
    if ((tid & 63) == 0) { sred[grp][wv][0] = sum; sred[grp][wv][1] = sq; }
    __syncthreads();
    if (valid) {
      const float ts = sred[grp][0][0] + sred[grp][1][0];
      const float tq = sred[grp][0][1] + sred[grp][1][1];
      const float mu = ts * (1.f/128.f);
      const float var = tq * (1.f/128.f) - mu*mu;
      const float rs = rsqrtf(var + 1e-5f);
      ea[(long)row*128 + lt] = f2bf((v - mu) * rs * g[lt] + bb[lt]);
    }
    __syncthreads();
  }
}

// --------- 128x128 linear: out(bf16) = in(fp32) @ w.T + b ---------
__global__ __launch_bounds__(256) void linear128_kernel(
    const float* __restrict__ in, const float* __restrict__ w,
    const float* __restrict__ b, u16* __restrict__ out, int n)
{
  __shared__ u32 swp[64*128];   // packed bf16 pairs along k: swp[kk*128+c]
  const int tid = threadIdx.x;
  for (int i = tid; i < 8192; i += blockDim.x) {
    int c = i >> 6, kk = i & 63;
    swp[kk*128 + c] = packbf(w[c*128 + 2*kk], w[c*128 + 2*kk + 1]);
  }
  __syncthreads();
  const int lane = tid & 63, wv = tid >> 6;
  const int wpb = blockDim.x >> 6;
  const float b0 = b[lane], b1v = b[lane + 64];
  for (long row = (long)blockIdx.x*wpb + wv; row < n; row += (long)gridDim.x*wpb) {
    const float* ir = in + row*128;
    float a0 = b0, a1 = b1v;
    #pragma unroll 8
    for (int kk = 0; kk < 64; ++kk) {
      const float v0 = ir[2*kk], v1 = ir[2*kk + 1];
      const u32 w0 = swp[kk*128 + lane];
      const u32 w1 = swp[kk*128 + lane + 64];
      a0 += v0*bflo(w0) + v1*bfhi(w0);
      a1 += v0*bflo(w1) + v1*bfhi(w1);
    }
    out[row*128 + lane]      = f2bf(a0);
    out[row*128 + lane + 64] = f2bf(a1);
  }
}

// ---------------- CSR build ----------------
__global__ __launch_bounds__(256) void csr_count_kernel(
    const int* __restrict__ dst, int* __restrict__ cnt, int E)
{
  for (long e = (long)blockIdx.x*blockDim.x + threadIdx.x; e < E;
       e += (long)gridDim.x*blockDim.x)
    atomicAdd(&cnt[dst[e]], 1);
}

__global__ __launch_bounds__(1024) void csr_scan_kernel(
    const int* __restrict__ cnt, int* __restrict__ rowptr, int n)
{
  __shared__ int part[1024];
  const int t = threadIdx.x;
  const int chunk = (n + 1023) >> 10;
  const int b = t * chunk;
  const int e = min(b + chunk, n);
  int s = 0;
  for (int i = b; i < e; ++i) s += cnt[i];
  part[t] = s;
  __syncthreads();
  for (int d = 1; d < 1024; d <<= 1) {
    int v = (t >= d) ? part[t - d] : 0;
    __syncthreads();
    if (t >= d) part[t] += v;
    __syncthreads();
  }
  int pre = (t == 0) ? 0 : part[t - 1];
  for (int i = b; i < e; ++i) { rowptr[i] = pre; pre += cnt[i]; }
  if (t == 1023) rowptr[n] = pre;
}

__global__ __launch_bounds__(256) void csr_fill_kernel(
    const int* __restrict__ dst, const int* __restrict__ rowptr,
    int* __restrict__ cursor, int* __restrict__ eid, int E)
{
  for (long e = (long)blockIdx.x*blockDim.x + threadIdx.x; e < E;
       e += (long)gridDim.x*blockDim.x) {
    const int d = dst[e];
    const int pos = atomicAdd(&cursor[d], 1);
    eid[rowptr[d] + pos] = (int)e;
  }
}

// -------- per-edge attention logit s[e] (no atomics) --------
__global__ __launch_bounds__(256) void gat_logit_kernel(
    const u16* __restrict__ ea,         // chunk base (local rows)
    const u16* __restrict__ xl, const u16* __restrict__ xr,
    const int* __restrict__ src, const int* __restrict__ dst,
    const float* __restrict__ we, const float* __restrict__ att,
    float* __restrict__ s_out, int eoff, int ecnt)
{
  __shared__ u32 swp[64*128];   // packed bf16 we pairs along k
  const int tid = threadIdx.x;
  for (int i = tid; i < 8192; i += blockDim.x) {
    int c = i >> 6, kk = i & 63;
    swp[kk*128 + c] = packbf(we[c*128 + 2*kk], we[c*128 + 2*kk + 1]);
  }
  __syncthreads();
  const int lane = tid & 63, wv = tid >> 6;
  const int wpb = blockDim.x >> 6;
  const long totalWaves = (long)gridDim.x * wpb;
  const float att0 = att[lane], att1 = att[lane + 64];
  for (long i = (long)blockIdx.x*wpb + wv; i < ecnt; i += totalWaves) {
    const long e = eoff + i;
    const int sN = src[e], dN = dst[e];
    const u32* eap = (const u32*)(ea + i*128);
    float a0 = 0.f, a1 = 0.f;
    #pragma unroll 8
    for (int kk = 0; kk < 64; ++kk) {
      const u32 va = eap[kk];
      const float v0 = bflo(va), v1 = bfhi(va);
      const u32 w0 = swp[kk*128 + lane];
      const u32 w1 = swp[kk*128 + lane + 64];
      a0 += v0*bflo(w0) + v1*bfhi(w0);
      a1 += v0*bflo(w1) + v1*bfhi(w1);
    }
    float e0 = a0 + bf2f(xl[(long)sN*128 + lane])      + bf2f(xr[(long)dN*128 + lane]);
    float e1 = a1 + bf2f(xl[(long)sN*128 + lane + 64]) + bf2f(xr[(long)dN*128 + lane + 64]);
    e0 = LEAKY20(e0); e1 = LEAKY20(e1);
    float p = e0*att0 + e1*att1;
    for (int off = 32; off; off >>= 1) p += __shfl_down(p, off, 64);
    if (lane == 0) s_out[e] = p;
  }
}

// ---- per-node: softmax over CSR edges + weighted gather + LN residual ----
__global__ __launch_bounds__(256) void gat_agg_kernel(
    const float* __restrict__ s, const int* __restrict__ src,
    const int* __restrict__ rowptr, const int* __restrict__ eid,
    const u16* __restrict__ xl, const float* __restrict__ bias,
    const float* __restrict__ g, const float* __restrict__ bb,
    float* __restrict__ y, int n)
{
  const int tid = threadIdx.x;
  const int lane = tid & 63, wv = tid >> 6;
  const int wpb = blockDim.x >> 6;
  const float bi0 = bias[lane], bi1 = bias[lane + 64];
  const float g0 = g[lane], g1 = g[lane + 64];
  const float bb0 = bb[lane], bb1 = bb[lane + 64];
  for (long node = (long)blockIdx.x*wpb + wv; node < n; node += (long)gridDim.x*wpb) {
    const int beg = rowptr[node], end = rowptr[node + 1];
    float m = -INFINITY;
    for (int j = beg; j < end; ++j) m = fmaxf(m, s[eid[j]]);
    float den = 0.f, a0 = 0.f, a1 = 0.f;
    for (int j = beg; j < end; ++j) {
      const int e = eid[j];
      const float z = __expf(s[e] - m);
      den += z;
      const int sN = src[e];
      a0 += z * bf2f(xl[(long)sN*128 + lane]);
      a1 += z * bf2f(xl[(long)sN*128 + lane + 64]);
    }
    const float inv = 1.f / fmaxf(den, 1e-16f);
    const float v0 = a0*inv + bi0;
    const float v1 = a1*inv + bi1;
    float sum = v0 + v1, sq = v0*v0 + v1*v1;
    for (int off = 32; off; off >>= 1) { sum += __shfl_xor(sum, off, 64); sq += __shfl_xor(sq, off, 64); }
    const float mu = sum * (1.f/128.f);
    const float var = sq * (1.f/128.f) - mu*mu;
    const float rs = rsqrtf(var + 1e-5f);
    y[node*128 + lane]      += (v0 - mu) * rs * g0 + bb0;
    y[node*128 + lane + 64] += (v1 - mu) * rs * g1 + bb1;
  }
}

// ---------------- decoder: 128 -> 86 -> 44 -> 2 ----------------
__global__ __launch_bounds__(256) void decoder_kernel(
    const float* __restrict__ y,
    const float* __restrict__ w1, const float* __restrict__ b1,
    const float* __restrict__ w2, const float* __restrict__ b2,
    const float* __restrict__ w3, const float* __restrict__ b3,
    float* __restrict__ out, int n)
{
  __shared__ float sw1t[128*86];
  __shared__ float sw2t[86*44];
  __shared__ float sw3t[44*2];
  __shared__ float sh1[2][86];
  __shared__ float sh2[2][44];
  const int tid = threadIdx.x;
  for (int i = tid; i < 86*128; i += blockDim.x) { int j = i >> 7, k = i & 127;  sw1t[k*86 + j] = w1[i]; }
  for (int i = tid; i < 44*86; i += blockDim.x)  { int j = i / 86, k = i - j*86; sw2t[k*44 + j] = w2[i]; }
  for (int i = tid; i < 2*44; i += blockDim.x)   { int j = i / 44, k = i - j*44; sw3t[k*2 + j]  = w3[i]; }
  __syncthreads();
  const int grp = tid >> 7, lt = tid & 127;
  const int rowsPerIter = gridDim.x * 2;
  const int iters = (n + rowsPerIter - 1) / rowsPerIter;
  for (int it = 0; it < iters; ++it) {
    const int row = blockIdx.x*2 + it*rowsPerIter + grp;
    const bool valid = row < n;
    if (valid && lt < 86) {
      const float* yr = y + (long)row*128;
      float a = b1[lt];
      #pragma unroll 8
      for (int k = 0; k < 128; ++k) a += yr[k] * sw1t[k*86 + lt];
      sh1[grp][lt] = LEAKY01(a);
    }
    __syncthreads();
    if (valid && lt < 44) {
      float a = b2[lt];
      #pragma unroll 8
      for (int k = 0; k < 86; ++k) a += sh1[grp][k] * sw2t[k*44 + lt];
      sh2[grp][lt] = LEAKY01(a);
    }
    __syncthreads();
    if (valid && lt < 2) {
      float a = b3[lt];
      #pragma unroll
      for (int k = 0; k < 44; ++k) a += sh2[grp][k] * sw3t[k*2 + lt];
      out[(long)row*2 + lt] = a;
    }
    __syncthreads();
  }
}

__global__ __launch_bounds__(256) void zero_out_kernel(float* __restrict__ out, long n)
{
  for (long i = (long)blockIdx.x*blockDim.x + threadIdx.x; i < n;
       i += (long)gridDim.x*blockDim.x) out[i] = 0.f;
}

// ---------------------------------------------------------------------------
extern "C" void kernel_launch(void* const* d_in, const int* in_sizes, int n_in,
                              void* d_out, int out_size, void* d_ws, size_t ws_size,
                              hipStream_t stream) {
  const float* x        = (const float*)d_in[0];
  const int*   eidx     = (const int*)  d_in[1];
  const float* edge_attr= (const float*)d_in[2];
  const float* enc_w1 = (const float*)d_in[3];  const float* enc_b1 = (const float*)d_in[4];
  const float* enc_w2 = (const float*)d_in[5];  const float* enc_b2 = (const float*)d_in[6];
  const float* enc_w3 = (const float*)d_in[7];  const float* enc_b3 = (const float*)d_in[8];
  const float* enc_lg = (const float*)d_in[9];  const float* enc_lb = (const float*)d_in[10];
  const float* ee_w1  = (const float*)d_in[11]; const float* ee_b1  = (const float*)d_in[12];
  const float* ee_w2  = (const float*)d_in[13]; const float* ee_b2  = (const float*)d_in[14];
  const float* ee_w3  = (const float*)d_in[15]; const float* ee_b3  = (const float*)d_in[16];
  const float* ee_lg  = (const float*)d_in[17]; const float* ee_lb  = (const float*)d_in[18];
  const float* gat_wl = (const float*)d_in[19]; const float* gat_bl = (const float*)d_in[20];
  const float* gat_wr = (const float*)d_in[21]; const float* gat_br = (const float*)d_in[22];
  const float* gat_we = (const float*)d_in[23]; const float* gat_att= (const float*)d_in[24];
  const float* gat_bias=(const float*)d_in[25];
  const float* ln_g   = (const float*)d_in[26]; const float* ln_b   = (const float*)d_in[27];
  const float* dec_w1 = (const float*)d_in[28]; const float* dec_b1 = (const float*)d_in[29];
  const float* dec_w2 = (const float*)d_in[30]; const float* dec_b2 = (const float*)d_in[31];
  const float* dec_w3 = (const float*)d_in[32]; const float* dec_b3 = (const float*)d_in[33];
  float* out = (float*)d_out;

  const int N = in_sizes[0] / 32;
  const int E = in_sizes[2] / 8;
  const int L = in_sizes[19] / (128*128);
  const int* src = eidx;
  const int* dst = eidx + E;
  (void)n_in; (void)out_size;

  // ---- workspace carve, bounded by ws_size ----
  size_t off = 0;
  auto carve = [&](size_t bytes) -> char* {
    char* r = (char*)d_ws + off;
    off += (bytes + 255) & ~(size_t)255;
    return r;
  };
  float* y      = (float*)carve((size_t)N * 128 * 4);   // 25.6 MB
  u16*   xl     = (u16*)  carve((size_t)N * 128 * 2);   // 12.8 MB
  u16*   xr     = (u16*)  carve((size_t)N * 128 * 2);   // 12.8 MB
  float* sbuf   = (float*)carve((size_t)E * 4);         //  3.2 MB
  int*   rowptr = (int*)  carve((size_t)(N + 1) * 4);
  int*   eidbuf = (int*)  carve((size_t)E * 4);         //  3.2 MB
  int*   cnt    = (int*)  carve((size_t)N * 4);
  int*   cursor = (int*)  carve((size_t)N * 4);
  const size_t fixedBytes = off;

  if (ws_size < fixedBytes + (size_t)4096 * 256) {
    // cannot run at all: emit zeros deterministically (diagnostic fallback)
    hipLaunchKernelGGL(zero_out_kernel, dim3(256), dim3(256), 0, stream, out, (long)N*2);
    return;
  }
  const size_t eaCapEdges = (ws_size - fixedBytes) / 256;  // bytes per bf16 row = 256
  u16* eaBuf = (u16*)((char*)d_ws + fixedBytes);
  const bool full = eaCapEdges >= (size_t)E;
  const int Ec = full ? E : (int)(eaCapEdges & ~(size_t)1023);

  // ---- node encoder + CSR build (dst is layer-invariant) ----
  hipLaunchKernelGGL(node_enc_kernel, dim3(512), dim3(256), 0, stream,
                     x, enc_w1, enc_b1, enc_w2, enc_b2, enc_w3, enc_b3,
                     enc_lg, enc_lb, y, N);
  hipMemsetAsync(cnt, 0, (size_t)N * 4, stream);
  hipMemsetAsync(cursor, 0, (size_t)N * 4, stream);
  hipLaunchKernelGGL(csr_count_kernel, dim3(1024), dim3(256), 0, stream, dst, cnt, E);
  hipLaunchKernelGGL(csr_scan_kernel, dim3(1), dim3(1024), 0, stream, cnt, rowptr, N);
  hipLaunchKernelGGL(csr_fill_kernel, dim3(1024), dim3(256), 0, stream, dst, rowptr, cursor, eidbuf, E);

  if (full) {
    hipLaunchKernelGGL(edge_enc_kernel, dim3(2048), dim3(256), 0, stream,
                       edge_attr, ee_w1, ee_b1, ee_w2, ee_b2, ee_w3, ee_b3,
                       ee_lg, ee_lb, eaBuf, E);
  }

  for (int l = 0; l < L; ++l) {
    const float* wl = gat_wl + (size_t)l*128*128;
    const float* bl = gat_bl + (size_t)l*128;
    const float* wr = gat_wr + (size_t)l*128*128;
    const float* br = gat_br + (size_t)l*128;
    const float* we = gat_we + (size_t)l*128*128;
    const float* at = gat_att + (size_t)l*128;
    const float* bi = gat_bias + (size_t)l*128;
    const float* lg = ln_g + (size_t)l*128;
    const float* lb = ln_b + (size_t)l*128;

    hipLaunchKernelGGL(linear128_kernel, dim3(1024), dim3(256), 0, stream, y, wl, bl, xl, N);
    hipLaunchKernelGGL(linear128_kernel, dim3(1024), dim3(256), 0, stream, y, wr, br, xr, N);

    if (full) {
      hipLaunchKernelGGL(gat_logit_kernel, dim3(2048), dim3(256), 0, stream,
                         eaBuf, xl, xr, src, dst, we, at, sbuf, 0, E);
    } else {
      for (int eoff = 0; eoff < E; eoff += Ec) {
        const int c = (E - eoff < Ec) ? (E - eoff) : Ec;
        hipLaunchKernelGGL(edge_enc_kernel, dim3(1024), dim3(256), 0, stream,
                           edge_attr + (size_t)eoff*8, ee_w1, ee_b1, ee_w2, ee_b2,
                           ee_w3, ee_b3, ee_lg, ee_lb, eaBuf, c);
        hipLaunchKernelGGL(gat_logit_kernel, dim3(1024), dim3(256), 0, stream,
                           eaBuf, xl, xr, src, dst, we, at, sbuf, eoff, c);
      }
    }

    hipLaunchKernelGGL(gat_agg_kernel, dim3(1024), dim3(256), 0, stream,
                       sbuf, src, rowptr, eidbuf, xl, bi, lg, lb, y, N);
  }

  hipLaunchKernelGGL(decoder_kernel, dim3(1024), dim3(256), 0, stream,
                     y, dec_w1, dec_b1, dec_w2, dec_b2, dec_w3, dec_b3, out, N);
}